// Round 1
// baseline (2743.951 us; speedup 1.0000x reference)
//
#include <hip/hip_runtime.h>

#define NN 50000
#define NE_MAIN 800000
#define NE_CONT 200000

// ---------------------------------------------------------------- zero ----
__global__ __launch_bounds__(256) void zero_kernel(float4* __restrict__ p, int n4) {
  int i = blockIdx.x * 256 + threadIdx.x;
  int stride = gridDim.x * 256;
  float4 z = make_float4(0.f, 0.f, 0.f, 0.f);
  for (; i < n4; i += stride) p[i] = z;
}

// ---------------------------------------------------- tile GEMM helper ----
// dst[64][128] = act(src[64][128]) @ W[128][128] + b   (row-major W: W[k][n])
// 256 threads: thread tile = 4 rows x 8 cols.
template <bool RELU_IN>
__device__ __forceinline__ void tile_gemm(const float (* __restrict__ src)[132],
                                          float (* __restrict__ dst)[132],
                                          const float* __restrict__ W,
                                          const float* __restrict__ b,
                                          int tid) {
  const int eg = tid >> 4, cg = tid & 15;
  const int e0 = eg * 4, c0 = cg * 8;
  float acc[4][8];
  float4 bv0 = *(const float4*)(b + c0);
  float4 bv1 = *(const float4*)(b + c0 + 4);
#pragma unroll
  for (int r = 0; r < 4; ++r) {
    acc[r][0] = bv0.x; acc[r][1] = bv0.y; acc[r][2] = bv0.z; acc[r][3] = bv0.w;
    acc[r][4] = bv1.x; acc[r][5] = bv1.y; acc[r][6] = bv1.z; acc[r][7] = bv1.w;
  }
#pragma unroll 2
  for (int k = 0; k < 128; ++k) {
    float4 w0 = *(const float4*)(W + k * 128 + c0);
    float4 w1 = *(const float4*)(W + k * 128 + c0 + 4);
    float a[4];
#pragma unroll
    for (int r = 0; r < 4; ++r) {
      float v = src[e0 + r][k];
      a[r] = RELU_IN ? fmaxf(v, 0.f) : v;
    }
#pragma unroll
    for (int r = 0; r < 4; ++r) {
      acc[r][0] = fmaf(a[r], w0.x, acc[r][0]);
      acc[r][1] = fmaf(a[r], w0.y, acc[r][1]);
      acc[r][2] = fmaf(a[r], w0.z, acc[r][2]);
      acc[r][3] = fmaf(a[r], w0.w, acc[r][3]);
      acc[r][4] = fmaf(a[r], w1.x, acc[r][4]);
      acc[r][5] = fmaf(a[r], w1.y, acc[r][5]);
      acc[r][6] = fmaf(a[r], w1.z, acc[r][6]);
      acc[r][7] = fmaf(a[r], w1.w, acc[r][7]);
    }
  }
#pragma unroll
  for (int r = 0; r < 4; ++r) {
    *(float4*)(&dst[e0 + r][c0])     = make_float4(acc[r][0], acc[r][1], acc[r][2], acc[r][3]);
    *(float4*)(&dst[e0 + r][c0 + 4]) = make_float4(acc[r][4], acc[r][5], acc[r][6], acc[r][7]);
  }
}

// ------------------------------------------------------------ precompute ----
// xa_m = x @ mW0[8:136], xb_m = x @ mW0[136:264], xa_c = x @ cW0[4:132], xb_c = x @ cW0[132:260]
__device__ __forceinline__ void pc_gemm(const float (* __restrict__ sA)[132],
                                        const float* __restrict__ W,
                                        float* __restrict__ O,
                                        int n0, int tid) {
  const int eg = tid >> 4, cg = tid & 15;
  const int e0 = eg * 4, c0 = cg * 8;
  float acc[4][8];
#pragma unroll
  for (int r = 0; r < 4; ++r)
#pragma unroll
    for (int c = 0; c < 8; ++c) acc[r][c] = 0.f;
#pragma unroll 2
  for (int k = 0; k < 128; ++k) {
    float4 w0 = *(const float4*)(W + k * 128 + c0);
    float4 w1 = *(const float4*)(W + k * 128 + c0 + 4);
    float a[4];
#pragma unroll
    for (int r = 0; r < 4; ++r) a[r] = sA[e0 + r][k];
#pragma unroll
    for (int r = 0; r < 4; ++r) {
      acc[r][0] = fmaf(a[r], w0.x, acc[r][0]);
      acc[r][1] = fmaf(a[r], w0.y, acc[r][1]);
      acc[r][2] = fmaf(a[r], w0.z, acc[r][2]);
      acc[r][3] = fmaf(a[r], w0.w, acc[r][3]);
      acc[r][4] = fmaf(a[r], w1.x, acc[r][4]);
      acc[r][5] = fmaf(a[r], w1.y, acc[r][5]);
      acc[r][6] = fmaf(a[r], w1.z, acc[r][6]);
      acc[r][7] = fmaf(a[r], w1.w, acc[r][7]);
    }
  }
#pragma unroll
  for (int r = 0; r < 4; ++r) {
    int n = n0 + e0 + r;
    if (n < NN) {
      *(float4*)(O + (size_t)n * 128 + c0)     = make_float4(acc[r][0], acc[r][1], acc[r][2], acc[r][3]);
      *(float4*)(O + (size_t)n * 128 + c0 + 4) = make_float4(acc[r][4], acc[r][5], acc[r][6], acc[r][7]);
    }
  }
}

__global__ __launch_bounds__(256, 2) void precompute_kernel(
    const float* __restrict__ x,
    const float* __restrict__ mW0, const float* __restrict__ cW0,
    float* __restrict__ xa_m, float* __restrict__ xb_m,
    float* __restrict__ xa_c, float* __restrict__ xb_c) {
  __shared__ float sA[64][132];
  const int tid = threadIdx.x;
  const int n0 = blockIdx.x * 64;
#pragma unroll
  for (int it = 0; it < 8; ++it) {
    int t = it * 256 + tid;
    int e = t >> 5;
    int f4 = (t & 31) * 4;
    int n = n0 + e;
    float4 v = make_float4(0.f, 0.f, 0.f, 0.f);
    if (n < NN) v = *(const float4*)(x + (size_t)n * 128 + f4);
    *(float4*)(&sA[e][f4]) = v;
  }
  __syncthreads();
  pc_gemm(sA, mW0 + 8 * 128,   xa_m, n0, tid);
  pc_gemm(sA, mW0 + 136 * 128, xb_m, n0, tid);
  pc_gemm(sA, cW0 + 4 * 128,   xa_c, n0, tid);
  pc_gemm(sA, cW0 + 132 * 128, xb_c, n0, tid);
}

// ------------------------------------------------------------ edge MLP ----
// NF = 8 (main: [d,|d|,dw,|dw|]) or 4 (cont: [dw,|dw|]).
// h0 = xa[i] + xb[j] + b0 + feat @ W0f ; h1 = relu(h0)@W1+b1 ; h2 = relu(h1)@W2+b2
// agg[j] += LN(h2)
template <int NF>
__global__ __launch_bounds__(256, 2) void edge_kernel(
    const int* __restrict__ idx, int nE,
    const float* __restrict__ pp,
    const float* __restrict__ xa, const float* __restrict__ xb,
    const float* __restrict__ W0f, const float* __restrict__ b0v,
    const float* __restrict__ W1, const float* __restrict__ b1v,
    const float* __restrict__ W2, const float* __restrict__ b2v,
    float* __restrict__ agg) {
  __shared__ float sH0[64][132];
  __shared__ float sH1[64][132];
  __shared__ float sFeat[64][8];
  __shared__ int sI[64], sJ[64];
  __shared__ float sMean[64], sRn[64];
  const int tid = threadIdx.x;
  const int base = blockIdx.x * 64;

  if (tid < 64) {
    int e = base + tid;
    int i = idx[e];
    int j = idx[nE + e];
    sI[tid] = i; sJ[tid] = j;
    const float* pi = pp + (size_t)i * 6;
    const float* pj = pp + (size_t)j * 6;
    if (NF == 8) {
      float d0 = pi[0] - pj[0], d1 = pi[1] - pj[1], d2 = pi[2] - pj[2];
      sFeat[tid][0] = d0; sFeat[tid][1] = d1; sFeat[tid][2] = d2;
      sFeat[tid][3] = sqrtf(d0 * d0 + d1 * d1 + d2 * d2);
      float w0 = pi[3] - pj[3], w1 = pi[4] - pj[4], w2 = pi[5] - pj[5];
      sFeat[tid][4] = w0; sFeat[tid][5] = w1; sFeat[tid][6] = w2;
      sFeat[tid][7] = sqrtf(w0 * w0 + w1 * w1 + w2 * w2);
    } else {
      float w0 = pi[3] - pj[3], w1 = pi[4] - pj[4], w2 = pi[5] - pj[5];
      sFeat[tid][0] = w0; sFeat[tid][1] = w1; sFeat[tid][2] = w2;
      sFeat[tid][3] = sqrtf(w0 * w0 + w1 * w1 + w2 * w2);
    }
  }
  __syncthreads();

  // stage h0
#pragma unroll
  for (int it = 0; it < 8; ++it) {
    int t = it * 256 + tid;
    int e = t >> 5;
    int f4 = (t & 31) * 4;
    int i = sI[e], j = sJ[e];
    float4 va  = *(const float4*)(xa + (size_t)i * 128 + f4);
    float4 vb  = *(const float4*)(xb + (size_t)j * 128 + f4);
    float4 vb0 = *(const float4*)(b0v + f4);
    float4 v = make_float4(va.x + vb.x + vb0.x, va.y + vb.y + vb0.y,
                           va.z + vb.z + vb0.z, va.w + vb.w + vb0.w);
#pragma unroll
    for (int q = 0; q < NF; ++q) {
      float fq = sFeat[e][q];
      float4 w = *(const float4*)(W0f + q * 128 + f4);
      v.x = fmaf(fq, w.x, v.x);
      v.y = fmaf(fq, w.y, v.y);
      v.z = fmaf(fq, w.z, v.z);
      v.w = fmaf(fq, w.w, v.w);
    }
    *(float4*)(&sH0[e][f4]) = v;
  }
  __syncthreads();

  tile_gemm<true>(sH0, sH1, W1, b1v, tid);
  __syncthreads();
  tile_gemm<true>(sH1, sH0, W2, b2v, tid);
  __syncthreads();

  // layernorm stats: 4 lanes per edge row
  {
    int e = tid >> 2, sub = tid & 3;
    float s = 0.f, sq = 0.f;
#pragma unroll
    for (int q = 0; q < 32; ++q) {
      float v = sH0[e][sub * 32 + q];
      s += v; sq += v * v;
    }
    s += __shfl_xor(s, 1); sq += __shfl_xor(sq, 1);
    s += __shfl_xor(s, 2); sq += __shfl_xor(sq, 2);
    float mean = s * (1.f / 128.f);
    float var  = sq * (1.f / 128.f) - mean * mean;
    if (sub == 0) { sMean[e] = mean; sRn[e] = rsqrtf(var + 1e-5f); }
  }
  __syncthreads();

  // normalize + atomic scatter to agg[j]
#pragma unroll
  for (int it = 0; it < 8; ++it) {
    int t = it * 256 + tid;
    int e = t >> 5;
    int f4 = (t & 31) * 4;
    float4 v = *(const float4*)(&sH0[e][f4]);
    float mean = sMean[e], rn = sRn[e];
    float* dstp = agg + (size_t)sJ[e] * 128 + f4;
    unsafeAtomicAdd(dstp + 0, (v.x - mean) * rn);
    unsafeAtomicAdd(dstp + 1, (v.y - mean) * rn);
    unsafeAtomicAdd(dstp + 2, (v.z - mean) * rn);
    unsafeAtomicAdd(dstp + 3, (v.w - mean) * rn);
  }
}

// ------------------------------------------------------------ node MLP ----
// out = LN(relu(relu([x,agg_m,agg_c]@W0+b0)@W1+b1)@W2+b2) + x
__global__ __launch_bounds__(256, 2) void node_kernel(
    const float* __restrict__ x,
    const float* __restrict__ agg_m, const float* __restrict__ agg_c,
    const float* __restrict__ W0, const float* __restrict__ b0v,
    const float* __restrict__ W1, const float* __restrict__ b1v,
    const float* __restrict__ W2, const float* __restrict__ b2v,
    float* __restrict__ out) {
  __shared__ float sA[64][132];
  __shared__ float sH[64][132];
  __shared__ float sMean[64], sRn[64];
  const int tid = threadIdx.x;
  const int n0 = blockIdx.x * 64;
  const int eg = tid >> 4, cg = tid & 15;
  const int e0 = eg * 4, c0 = cg * 8;

  float acc[4][8];
  {
    float4 bv0 = *(const float4*)(b0v + c0);
    float4 bv1 = *(const float4*)(b0v + c0 + 4);
#pragma unroll
    for (int r = 0; r < 4; ++r) {
      acc[r][0] = bv0.x; acc[r][1] = bv0.y; acc[r][2] = bv0.z; acc[r][3] = bv0.w;
      acc[r][4] = bv1.x; acc[r][5] = bv1.y; acc[r][6] = bv1.z; acc[r][7] = bv1.w;
    }
  }

#pragma unroll
  for (int p = 0; p < 3; ++p) {
    const float* src = (p == 0) ? x : (p == 1) ? agg_m : agg_c;
#pragma unroll
    for (int it = 0; it < 8; ++it) {
      int t = it * 256 + tid;
      int e = t >> 5;
      int f4 = (t & 31) * 4;
      int n = n0 + e;
      float4 v = make_float4(0.f, 0.f, 0.f, 0.f);
      if (n < NN) v = *(const float4*)(src + (size_t)n * 128 + f4);
      *(float4*)(&sA[e][f4]) = v;
    }
    __syncthreads();
    const float* W = W0 + p * 128 * 128;
#pragma unroll 2
    for (int k = 0; k < 128; ++k) {
      float4 w0 = *(const float4*)(W + k * 128 + c0);
      float4 w1 = *(const float4*)(W + k * 128 + c0 + 4);
      float a[4];
#pragma unroll
      for (int r = 0; r < 4; ++r) a[r] = sA[e0 + r][k];
#pragma unroll
      for (int r = 0; r < 4; ++r) {
        acc[r][0] = fmaf(a[r], w0.x, acc[r][0]);
        acc[r][1] = fmaf(a[r], w0.y, acc[r][1]);
        acc[r][2] = fmaf(a[r], w0.z, acc[r][2]);
        acc[r][3] = fmaf(a[r], w0.w, acc[r][3]);
        acc[r][4] = fmaf(a[r], w1.x, acc[r][4]);
        acc[r][5] = fmaf(a[r], w1.y, acc[r][5]);
        acc[r][6] = fmaf(a[r], w1.z, acc[r][6]);
        acc[r][7] = fmaf(a[r], w1.w, acc[r][7]);
      }
    }
    __syncthreads();
  }

  // park h0 (pre-activation) in sA
#pragma unroll
  for (int r = 0; r < 4; ++r) {
    *(float4*)(&sA[e0 + r][c0])     = make_float4(acc[r][0], acc[r][1], acc[r][2], acc[r][3]);
    *(float4*)(&sA[e0 + r][c0 + 4]) = make_float4(acc[r][4], acc[r][5], acc[r][6], acc[r][7]);
  }
  __syncthreads();

  tile_gemm<true>(sA, sH, W1, b1v, tid);
  __syncthreads();
  tile_gemm<true>(sH, sA, W2, b2v, tid);
  __syncthreads();

  {
    int e = tid >> 2, sub = tid & 3;
    float s = 0.f, sq = 0.f;
#pragma unroll
    for (int q = 0; q < 32; ++q) {
      float v = sA[e][sub * 32 + q];
      s += v; sq += v * v;
    }
    s += __shfl_xor(s, 1); sq += __shfl_xor(sq, 1);
    s += __shfl_xor(s, 2); sq += __shfl_xor(sq, 2);
    float mean = s * (1.f / 128.f);
    float var  = sq * (1.f / 128.f) - mean * mean;
    if (sub == 0) { sMean[e] = mean; sRn[e] = rsqrtf(var + 1e-5f); }
  }
  __syncthreads();

#pragma unroll
  for (int it = 0; it < 8; ++it) {
    int t = it * 256 + tid;
    int e = t >> 5;
    int f4 = (t & 31) * 4;
    int n = n0 + e;
    if (n < NN) {
      float4 v  = *(const float4*)(&sA[e][f4]);
      float4 xv = *(const float4*)(x + (size_t)n * 128 + f4);
      float mean = sMean[e], rn = sRn[e];
      float4 o = make_float4((v.x - mean) * rn + xv.x, (v.y - mean) * rn + xv.y,
                             (v.z - mean) * rn + xv.z, (v.w - mean) * rn + xv.w);
      *(float4*)(out + (size_t)n * 128 + f4) = o;
    }
  }
}

// -------------------------------------------------------------- launch ----
extern "C" void kernel_launch(void* const* d_in, const int* in_sizes, int n_in,
                              void* d_out, int out_size, void* d_ws, size_t ws_size,
                              hipStream_t stream) {
  const float* x   = (const float*)d_in[0];
  const int*   g   = (const int*)d_in[1];
  const int*   cgr = (const int*)d_in[2];
  const float* pp  = (const float*)d_in[3];
  const float* mW0 = (const float*)d_in[4];
  const float* mb0 = (const float*)d_in[5];
  const float* mW1 = (const float*)d_in[6];
  const float* mb1 = (const float*)d_in[7];
  const float* mW2 = (const float*)d_in[8];
  const float* mb2 = (const float*)d_in[9];
  const float* cW0 = (const float*)d_in[10];
  const float* cb0 = (const float*)d_in[11];
  const float* cW1 = (const float*)d_in[12];
  const float* cb1 = (const float*)d_in[13];
  const float* cW2 = (const float*)d_in[14];
  const float* cb2 = (const float*)d_in[15];
  const float* nW0 = (const float*)d_in[16];
  const float* nb0 = (const float*)d_in[17];
  const float* nW1 = (const float*)d_in[18];
  const float* nb1 = (const float*)d_in[19];
  const float* nW2 = (const float*)d_in[20];
  const float* nb2 = (const float*)d_in[21];
  float* out = (float*)d_out;

  // workspace layout (floats): xa_m | xb_m | xa_c | xb_c | agg_m | agg_c  (153.6 MB)
  float* ws = (float*)d_ws;
  const size_t NL = (size_t)NN * 128;
  float* xa_m  = ws;
  float* xb_m  = xa_m + NL;
  float* xa_c  = xb_m + NL;
  float* xb_c  = xa_c + NL;
  float* agg_m = xb_c + NL;
  float* agg_c = agg_m + NL;

  zero_kernel<<<2048, 256, 0, stream>>>((float4*)agg_m, (int)(2 * NL / 4));
  precompute_kernel<<<(NN + 63) / 64, 256, 0, stream>>>(x, mW0, cW0, xa_m, xb_m, xa_c, xb_c);
  edge_kernel<8><<<NE_MAIN / 64, 256, 0, stream>>>(g, NE_MAIN, pp, xa_m, xb_m,
                                                   mW0, mb0, mW1, mb1, mW2, mb2, agg_m);
  edge_kernel<4><<<NE_CONT / 64, 256, 0, stream>>>(cgr, NE_CONT, pp, xa_c, xb_c,
                                                   cW0, cb0, cW1, cb1, cW2, cb2, agg_c);
  node_kernel<<<(NN + 63) / 64, 256, 0, stream>>>(x, agg_m, agg_c,
                                                  nW0, nb0, nW1, nb1, nW2, nb2, out);
}

// Round 2
// 773.992 us; speedup vs baseline: 3.5452x; 3.5452x over previous
//
#include <hip/hip_runtime.h>

#define NN 50000
#define NE_MAIN 800000
#define NE_CONT 200000

typedef __attribute__((ext_vector_type(8))) short bf8;   // 8 x bf16 (4 VGPRs)
typedef __attribute__((ext_vector_type(4))) float f4;    // 4 x f32

static __device__ __forceinline__ float bf2f(short s) {
  return __builtin_bit_cast(float, ((unsigned int)(unsigned short)s) << 16);
}
static __device__ __forceinline__ short f2bf(float f) {
  unsigned int u = __builtin_bit_cast(unsigned int, f);
  u += 0x7fffu + ((u >> 16) & 1u);   // RNE
  return (short)(u >> 16);
}

// ---------------------------------------------------------------- zero ----
__global__ __launch_bounds__(256) void zero_kernel(f4* __restrict__ p, int n4) {
  int i = blockIdx.x * 256 + threadIdx.x;
  int stride = gridDim.x * 256;
  f4 z = {0.f, 0.f, 0.f, 0.f};
  for (; i < n4; i += stride) p[i] = z;
}

// --------------------------------------------------- weight transpose ----
// dst[n][k] (bf16) = src[k][n] (f32); 11 matrices packed into one buffer.
struct WTDesc {
  const float* src[11];
  int K[11];
  int off[11];
};
__global__ __launch_bounds__(128) void wt_kernel(WTDesc d, short* __restrict__ dst) {
  int m = blockIdx.x >> 7;
  int n = blockIdx.x & 127;
  const float* s = d.src[m];
  int K = d.K[m];
  short* o = dst + d.off[m] + (size_t)n * K;
  for (int k = threadIdx.x; k < K; k += 128) o[k] = f2bf(s[(size_t)k * 128 + n]);
}

// ------------------------------------------------------- MFMA helpers ----
// 64-row tile in LDS (bf16, 16B-chunk XOR swizzle: chunk ^= row&7).
// Each wave computes all 64 rows x 32 cols (c0..c0+31).
// A-frag: row = lane&15 (+rf*16), k = (lane>>4)*8 + j (+ks*32)
// B-frag: col = lane&15 (+cf*16), same k pattern, loaded from WT[N][K].
// C/D  : col = lane&15, row = (lane>>4)*4 + reg  [HW-verified]
template <int K>
static __device__ __forceinline__ void mfma_gemm(const short* __restrict__ sA, int rs16,
                                                 const short* __restrict__ WT,
                                                 int c0, int lane,
                                                 const float* __restrict__ bias,
                                                 f4 (&acc)[4][2]) {
  const int colA = c0 + (lane & 15);
  const int colB = colA + 16;
  if (bias) {
    float ba = bias[colA], bb = bias[colB];
#pragma unroll
    for (int rf = 0; rf < 4; ++rf) {
      acc[rf][0] = (f4){ba, ba, ba, ba};
      acc[rf][1] = (f4){bb, bb, bb, bb};
    }
  } else {
#pragma unroll
    for (int rf = 0; rf < 4; ++rf) {
      acc[rf][0] = (f4){0.f, 0.f, 0.f, 0.f};
      acc[rf][1] = (f4){0.f, 0.f, 0.f, 0.f};
    }
  }
  const int g = lane >> 4;
  const int rowl = lane & 15;
#pragma unroll 4
  for (int ks = 0; ks < (K >> 5); ++ks) {
    bf8 b0 = *reinterpret_cast<const bf8*>(WT + (size_t)colA * K + ks * 32 + g * 8);
    bf8 b1 = *reinterpret_cast<const bf8*>(WT + (size_t)colB * K + ks * 32 + g * 8);
    int chunk = ks * 4 + g;
#pragma unroll
    for (int rf = 0; rf < 4; ++rf) {
      int row = rf * 16 + rowl;
      bf8 a = *reinterpret_cast<const bf8*>(sA + row * rs16 * 8 + ((chunk ^ (row & 7)) << 3));
      acc[rf][0] = __builtin_amdgcn_mfma_f32_16x16x32_bf16(a, b0, acc[rf][0], 0, 0, 0);
      acc[rf][1] = __builtin_amdgcn_mfma_f32_16x16x32_bf16(a, b1, acc[rf][1], 0, 0, 0);
    }
  }
}

// store accumulator frags as bf16 into LDS tile (optionally relu, optionally swizzled)
template <bool RELU, bool SWZ>
static __device__ __forceinline__ void store_frags(short* __restrict__ dst, int rs16,
                                                   int c0, int lane, const f4 (&acc)[4][2]) {
#pragma unroll
  for (int rf = 0; rf < 4; ++rf)
#pragma unroll
    for (int q = 0; q < 4; ++q) {
      int row = rf * 16 + ((lane >> 4) << 2) + q;
#pragma unroll
      for (int cf = 0; cf < 2; ++cf) {
        int col = c0 + cf * 16 + (lane & 15);
        float v = acc[rf][cf][q];
        if (RELU) v = fmaxf(v, 0.f);
        int idx;
        if (SWZ) idx = row * rs16 * 8 + (((col >> 3) ^ (row & 7)) << 3) + (col & 7);
        else     idx = row * rs16 * 8 + col;
        dst[idx] = f2bf(v);
      }
    }
}

// per-row sum/sumsq over this wave's 32 cols -> sP[wave*64+row]
static __device__ __forceinline__ void ln_rows(const f4 (&acc)[4][2], int lane, int wave,
                                               float2* __restrict__ sP) {
#pragma unroll
  for (int rf = 0; rf < 4; ++rf)
#pragma unroll
    for (int q = 0; q < 4; ++q) {
      float v0 = acc[rf][0][q], v1 = acc[rf][1][q];
      float s = v0 + v1;
      float qq = v0 * v0 + v1 * v1;
      s += __shfl_xor(s, 1);  qq += __shfl_xor(qq, 1);
      s += __shfl_xor(s, 2);  qq += __shfl_xor(qq, 2);
      s += __shfl_xor(s, 4);  qq += __shfl_xor(qq, 4);
      s += __shfl_xor(s, 8);  qq += __shfl_xor(qq, 8);
      if ((lane & 15) == 0) {
        int row = rf * 16 + ((lane >> 4) << 2) + q;
        sP[wave * 64 + row] = make_float2(s, qq);
      }
    }
}

// ------------------------------------------------------------ precompute ----
// xa/xb tables (bf16): x @ W0-slices. WTp holds 4 transposed 128x128 slices.
__global__ __launch_bounds__(256) void precompute_kernel(
    const float* __restrict__ x, const short* __restrict__ WTp,
    short* __restrict__ xa_m, short* __restrict__ xb_m,
    short* __restrict__ xa_c, short* __restrict__ xb_c) {
  __shared__ __align__(16) short sA[64 * 128];
  __shared__ __align__(16) short sOut[64 * 128];
  const int tid = threadIdx.x;
  const int lane = tid & 63, wave = tid >> 6;
  const int c0 = wave * 32;
  const int n0 = blockIdx.x * 64;

#pragma unroll
  for (int it = 0; it < 4; ++it) {
    int s = it * 256 + tid;
    int e = s >> 4, c = s & 15;
    int n = n0 + e;
    f4 u0 = {0.f, 0.f, 0.f, 0.f}, u1 = {0.f, 0.f, 0.f, 0.f};
    if (n < NN) {
      u0 = *reinterpret_cast<const f4*>(x + (size_t)n * 128 + c * 8);
      u1 = *reinterpret_cast<const f4*>(x + (size_t)n * 128 + c * 8 + 4);
    }
    bf8 o;
#pragma unroll
    for (int j = 0; j < 4; ++j) { o[j] = f2bf(u0[j]); o[j + 4] = f2bf(u1[j]); }
    *reinterpret_cast<bf8*>(sA + e * 128 + ((c ^ (e & 7)) << 3)) = o;
  }
  __syncthreads();

  short* dsts[4] = {xa_m, xb_m, xa_c, xb_c};
#pragma unroll 1
  for (int o = 0; o < 4; ++o) {
    f4 acc[4][2];
    mfma_gemm<128>(sA, 16, WTp + o * 16384, c0, lane, nullptr, acc);
    store_frags<false, false>(sOut, 16, c0, lane, acc);
    __syncthreads();
    short* dst = dsts[o];
#pragma unroll
    for (int it = 0; it < 4; ++it) {
      int s = it * 256 + tid;
      int e = s >> 4, c = s & 15;
      int n = n0 + e;
      if (n < NN)
        *reinterpret_cast<bf8*>(dst + (size_t)n * 128 + c * 8) =
            *reinterpret_cast<const bf8*>(sOut + e * 128 + c * 8);
    }
    __syncthreads();
  }
}

// ------------------------------------------------------------ edge MLP ----
template <int NF>
__global__ __launch_bounds__(256) void edge_kernel(
    const int* __restrict__ idx, int nE, const float* __restrict__ pp,
    const short* __restrict__ xa, const short* __restrict__ xb,
    const float* __restrict__ W0f, const float* __restrict__ b0v,
    const short* __restrict__ WT1, const float* __restrict__ b1v,
    const short* __restrict__ WT2, const float* __restrict__ b2v,
    float* __restrict__ agg) {
  __shared__ __align__(16) short sA[64 * 128];
  __shared__ __align__(16) short sB[64 * 128];
  __shared__ int sI[64], sJ[64];
  __shared__ float sF[64][NF];
  __shared__ float2 sP[4 * 64];
  __shared__ float2 sStats[64];
  const int tid = threadIdx.x;
  const int lane = tid & 63, wave = tid >> 6;
  const int c0 = wave * 32;
  const int base = blockIdx.x * 64;

  if (tid < 64) {
    int e = base + tid;
    int i = idx[e];
    int j = idx[nE + e];
    sI[tid] = i; sJ[tid] = j;
    const float* pi = pp + (size_t)i * 6;
    const float* pj = pp + (size_t)j * 6;
    if (NF == 8) {
      float d0 = pi[0] - pj[0], d1 = pi[1] - pj[1], d2 = pi[2] - pj[2];
      sF[tid][0] = d0; sF[tid][1] = d1; sF[tid][2] = d2;
      sF[tid][3] = sqrtf(d0 * d0 + d1 * d1 + d2 * d2);
      float w0 = pi[3] - pj[3], w1 = pi[4] - pj[4], w2 = pi[5] - pj[5];
      sF[tid][4] = w0; sF[tid][5] = w1; sF[tid][6] = w2;
      sF[tid][7] = sqrtf(w0 * w0 + w1 * w1 + w2 * w2);
    } else {
      float w0 = pi[3] - pj[3], w1 = pi[4] - pj[4], w2 = pi[5] - pj[5];
      sF[tid][0] = w0; sF[tid][1] = w1; sF[tid][2] = w2;
      sF[tid][3] = sqrtf(w0 * w0 + w1 * w1 + w2 * w2);
    }
  }
  __syncthreads();

  // stage h0 = relu(xa[i] + xb[j] + b0 + feat@W0f) as bf16 (swizzled)
#pragma unroll
  for (int it = 0; it < 4; ++it) {
    int s = it * 256 + tid;
    int e = s >> 4, c = s & 15;
    int i = sI[e], j = sJ[e];
    bf8 va = *reinterpret_cast<const bf8*>(xa + (size_t)i * 128 + c * 8);
    bf8 vb = *reinterpret_cast<const bf8*>(xb + (size_t)j * 128 + c * 8);
    f4 b0a = *reinterpret_cast<const f4*>(b0v + c * 8);
    f4 b0b = *reinterpret_cast<const f4*>(b0v + c * 8 + 4);
    float h[8];
#pragma unroll
    for (int jj = 0; jj < 4; ++jj) {
      h[jj]     = bf2f(va[jj])     + bf2f(vb[jj])     + b0a[jj];
      h[jj + 4] = bf2f(va[jj + 4]) + bf2f(vb[jj + 4]) + b0b[jj];
    }
#pragma unroll
    for (int q = 0; q < NF; ++q) {
      float fq = sF[e][q];
      f4 w0 = *reinterpret_cast<const f4*>(W0f + q * 128 + c * 8);
      f4 w1 = *reinterpret_cast<const f4*>(W0f + q * 128 + c * 8 + 4);
#pragma unroll
      for (int jj = 0; jj < 4; ++jj) {
        h[jj]     = fmaf(fq, w0[jj], h[jj]);
        h[jj + 4] = fmaf(fq, w1[jj], h[jj + 4]);
      }
    }
    bf8 o;
#pragma unroll
    for (int jj = 0; jj < 8; ++jj) o[jj] = f2bf(fmaxf(h[jj], 0.f));
    *reinterpret_cast<bf8*>(sA + e * 128 + ((c ^ (e & 7)) << 3)) = o;
  }
  __syncthreads();

  f4 acc[4][2];
  mfma_gemm<128>(sA, 16, WT1, c0, lane, b1v, acc);   // h1 = relu(h0)@W1+b1
  store_frags<true, true>(sB, 16, c0, lane, acc);
  __syncthreads();
  mfma_gemm<128>(sB, 16, WT2, c0, lane, b2v, acc);   // h2 = relu(h1)@W2+b2

  ln_rows(acc, lane, wave, sP);
  __syncthreads();
  if (tid < 64) {
    float s = 0.f, qq = 0.f;
#pragma unroll
    for (int w = 0; w < 4; ++w) { s += sP[w * 64 + tid].x; qq += sP[w * 64 + tid].y; }
    float mean = s * (1.f / 128.f);
    float var = qq * (1.f / 128.f) - mean * mean;
    sStats[tid] = make_float2(mean, rsqrtf(var + 1e-5f));
  }
  __syncthreads();

  // normalize + atomic scatter
#pragma unroll
  for (int rf = 0; rf < 4; ++rf)
#pragma unroll
    for (int q = 0; q < 4; ++q) {
      int row = rf * 16 + ((lane >> 4) << 2) + q;
      float mean = sStats[row].x, rn = sStats[row].y;
      float* bp = agg + (size_t)sJ[row] * 128;
#pragma unroll
      for (int cf = 0; cf < 2; ++cf) {
        int col = c0 + cf * 16 + (lane & 15);
        unsafeAtomicAdd(bp + col, (acc[rf][cf][q] - mean) * rn);
      }
    }
}

// ------------------------------------------------------------ node MLP ----
__global__ __launch_bounds__(256) void node_kernel(
    const float* __restrict__ x,
    const float* __restrict__ agg_m, const float* __restrict__ agg_c,
    const short* __restrict__ WT0, const float* __restrict__ b0v,
    const short* __restrict__ WT1, const float* __restrict__ b1v,
    const short* __restrict__ WT2, const float* __restrict__ b2v,
    float* __restrict__ out) {
  __shared__ __align__(16) short sA[64 * 384];
  __shared__ float2 sP[4 * 64];
  __shared__ float2 sStats[64];
  const int tid = threadIdx.x;
  const int lane = tid & 63, wave = tid >> 6;
  const int c0 = wave * 32;
  const int n0 = blockIdx.x * 64;

  // stage [x | agg_m | agg_c] -> bf16 swizzled, row stride 48 chunks
#pragma unroll
  for (int p = 0; p < 3; ++p) {
    const float* src = (p == 0) ? x : (p == 1) ? agg_m : agg_c;
#pragma unroll
    for (int it = 0; it < 4; ++it) {
      int s = it * 256 + tid;
      int e = s >> 4, cl = s & 15;
      int n = n0 + e;
      f4 u0 = {0.f, 0.f, 0.f, 0.f}, u1 = {0.f, 0.f, 0.f, 0.f};
      if (n < NN) {
        u0 = *reinterpret_cast<const f4*>(src + (size_t)n * 128 + cl * 8);
        u1 = *reinterpret_cast<const f4*>(src + (size_t)n * 128 + cl * 8 + 4);
      }
      bf8 o;
#pragma unroll
      for (int j = 0; j < 4; ++j) { o[j] = f2bf(u0[j]); o[j + 4] = f2bf(u1[j]); }
      int c = p * 16 + cl;
      *reinterpret_cast<bf8*>(sA + e * 384 + ((c ^ (e & 7)) << 3)) = o;
    }
  }
  __syncthreads();

  f4 acc[4][2];
  mfma_gemm<384>(sA, 48, WT0, c0, lane, b0v, acc);
  __syncthreads();                       // all reads of sA done before overwrite
  store_frags<true, true>(sA, 16, c0, lane, acc);        // h0r in shorts [0,8192)
  __syncthreads();
  mfma_gemm<128>(sA, 16, WT1, c0, lane, b1v, acc);
  __syncthreads();
  store_frags<true, true>(sA + 8192, 16, c0, lane, acc); // h1r in [8192,16384)
  __syncthreads();
  mfma_gemm<128>(sA + 8192, 16, WT2, c0, lane, b2v, acc);

  ln_rows(acc, lane, wave, sP);
  __syncthreads();
  if (tid < 64) {
    float s = 0.f, qq = 0.f;
#pragma unroll
    for (int w = 0; w < 4; ++w) { s += sP[w * 64 + tid].x; qq += sP[w * 64 + tid].y; }
    float mean = s * (1.f / 128.f);
    float var = qq * (1.f / 128.f) - mean * mean;
    sStats[tid] = make_float2(mean, rsqrtf(var + 1e-5f));
  }
  __syncthreads();

#pragma unroll
  for (int rf = 0; rf < 4; ++rf)
#pragma unroll
    for (int q = 0; q < 4; ++q) {
      int row = rf * 16 + ((lane >> 4) << 2) + q;
      int n = n0 + row;
      if (n < NN) {
        float mean = sStats[row].x, rn = sStats[row].y;
#pragma unroll
        for (int cf = 0; cf < 2; ++cf) {
          int col = c0 + cf * 16 + (lane & 15);
          float xv = x[(size_t)n * 128 + col];
          out[(size_t)n * 128 + col] = (acc[rf][cf][q] - mean) * rn + xv;
        }
      }
    }
}

// -------------------------------------------------------------- launch ----
extern "C" void kernel_launch(void* const* d_in, const int* in_sizes, int n_in,
                              void* d_out, int out_size, void* d_ws, size_t ws_size,
                              hipStream_t stream) {
  const float* x   = (const float*)d_in[0];
  const int*   g   = (const int*)d_in[1];
  const int*   cgr = (const int*)d_in[2];
  const float* pp  = (const float*)d_in[3];
  const float* mW0 = (const float*)d_in[4];
  const float* mb0 = (const float*)d_in[5];
  const float* mW1 = (const float*)d_in[6];
  const float* mb1 = (const float*)d_in[7];
  const float* mW2 = (const float*)d_in[8];
  const float* mb2 = (const float*)d_in[9];
  const float* cW0 = (const float*)d_in[10];
  const float* cb0 = (const float*)d_in[11];
  const float* cW1 = (const float*)d_in[12];
  const float* cb1 = (const float*)d_in[13];
  const float* cW2 = (const float*)d_in[14];
  const float* cb2 = (const float*)d_in[15];
  const float* nW0 = (const float*)d_in[16];
  const float* nb0 = (const float*)d_in[17];
  const float* nW1 = (const float*)d_in[18];
  const float* nb1 = (const float*)d_in[19];
  const float* nW2 = (const float*)d_in[20];
  const float* nb2 = (const float*)d_in[21];
  float* out = (float*)d_out;

  // workspace layout (bytes):
  // xa_m/xb_m/xa_c/xb_c bf16 (4 x 12.8MB) | agg_m/agg_c f32 (2 x 25.6MB) | WT bf16 (416KB)
  char* ws = (char*)d_ws;
  const size_t TBL = (size_t)NN * 128 * 2;       // 12.8 MB
  short* xa_m = (short*)(ws);
  short* xb_m = (short*)(ws + TBL);
  short* xa_c = (short*)(ws + 2 * TBL);
  short* xb_c = (short*)(ws + 3 * TBL);
  float* agg_m = (float*)(ws + 4 * TBL);
  float* agg_c = (float*)(ws + 4 * TBL + (size_t)NN * 128 * 4);
  short* wt = (short*)(ws + 4 * TBL + 2 * (size_t)NN * 128 * 4);

  // transposed-weight packing offsets (elements)
  // [0]mW1 [1]mW2 [2]cW1 [3]cW2 [4]nW0(K=384) [5]nW1 [6]nW2
  // [7]pm_a(mW0 r8..135) [8]pm_b(r136..263) [9]pc_a(cW0 r4..131) [10]pc_b(r132..259)
  WTDesc d;
  const float* srcs[11] = {mW1, mW2, cW1, cW2, nW0, nW1, nW2,
                           mW0 + 8 * 128, mW0 + 136 * 128, cW0 + 4 * 128, cW0 + 132 * 128};
  int Ks[11] = {128, 128, 128, 128, 384, 128, 128, 128, 128, 128, 128};
  int off = 0;
  for (int m = 0; m < 11; ++m) { d.src[m] = srcs[m]; d.K[m] = Ks[m]; d.off[m] = off; off += Ks[m] * 128; }
  short* wt1_m = wt + d.off[0];
  short* wt2_m = wt + d.off[1];
  short* wt1_c = wt + d.off[2];
  short* wt2_c = wt + d.off[3];
  short* wtn0  = wt + d.off[4];
  short* wtn1  = wt + d.off[5];
  short* wtn2  = wt + d.off[6];
  short* wtp   = wt + d.off[7];

  wt_kernel<<<11 * 128, 128, 0, stream>>>(d, wt);
  zero_kernel<<<2048, 256, 0, stream>>>((f4*)agg_m, (int)(2 * (size_t)NN * 128 / 4));
  precompute_kernel<<<(NN + 63) / 64, 256, 0, stream>>>(x, wtp, xa_m, xb_m, xa_c, xb_c);
  edge_kernel<8><<<NE_MAIN / 64, 256, 0, stream>>>(g, NE_MAIN, pp, xa_m, xb_m,
                                                   mW0, mb0, wt1_m, mb1, wt2_m, mb2, agg_m);
  edge_kernel<4><<<NE_CONT / 64, 256, 0, stream>>>(cgr, NE_CONT, pp, xa_c, xb_c,
                                                   cW0, cb0, wt1_c, cb1, wt2_c, cb2, agg_c);
  node_kernel<<<(NN + 63) / 64, 256, 0, stream>>>(x, agg_m, agg_c,
                                                  wtn0, nb0, wtn1, nb1, wtn2, nb2, out);
}

// Round 4
// 670.558 us; speedup vs baseline: 4.0920x; 1.1542x over previous
//
#include <hip/hip_runtime.h>

#define NN 50000
#define NE_MAIN 800000
#define NE_CONT 200000
#define NP 50176   // padded histogram size (>= NN)

typedef __attribute__((ext_vector_type(8))) short bf8;   // 8 x bf16 (4 VGPRs)
typedef __attribute__((ext_vector_type(4))) float f4;    // 4 x f32

static __device__ __forceinline__ float bf2f(short s) {
  return __builtin_bit_cast(float, ((unsigned int)(unsigned short)s) << 16);
}
static __device__ __forceinline__ short f2bf(float f) {
  unsigned int u = __builtin_bit_cast(unsigned int, f);
  u += 0x7fffu + ((u >> 16) & 1u);   // RNE
  return (short)(u >> 16);
}

// bijective XCD-chunked swizzle (m204 variant; works for nwg%8 != 0)
static __device__ __forceinline__ int xcd_swizzle(int bid, int nwg) {
  int xcd = bid & 7;
  int q = nwg >> 3, r = nwg & 7;
  int base = (xcd < r) ? xcd * (q + 1) : r * (q + 1) + (xcd - r) * q;
  return base + (bid >> 3);
}

// ---------------------------------------------------------------- zero ----
__global__ __launch_bounds__(256) void zero_kernel(f4* __restrict__ p, int n4) {
  int i = blockIdx.x * 256 + threadIdx.x;
  int stride = gridDim.x * 256;
  f4 z = {0.f, 0.f, 0.f, 0.f};
  for (; i < n4; i += stride) p[i] = z;
}

// ------------------------------------------------- counting sort by j ----
__global__ __launch_bounds__(256) void hist_kernel(const int* __restrict__ idx, int nE,
                                                   int* __restrict__ hist) {
  int e = blockIdx.x * 256 + threadIdx.x;
  int st = gridDim.x * 256;
  for (; e < nE; e += st) atomicAdd(&hist[idx[nE + e]], 1);
}

__global__ __launch_bounds__(512) void scan1_kernel(const int* __restrict__ hist,
                                                    int* __restrict__ cursor,
                                                    int* __restrict__ tsums, int n) {
  __shared__ int buf[2][512];
  int tid = threadIdx.x;
  int i = blockIdx.x * 512 + tid;
  int v = (i < n) ? hist[i] : 0;
  int cur = 0;
  buf[0][tid] = v;
  __syncthreads();
#pragma unroll
  for (int off = 1; off < 512; off <<= 1) {
    int t = buf[cur][tid];
    if (tid >= off) t += buf[cur][tid - off];
    buf[cur ^ 1][tid] = t;
    cur ^= 1;
    __syncthreads();
  }
  int incl = buf[cur][tid];
  if (i < n) cursor[i] = incl - v;           // exclusive within tile
  if (tid == 511) tsums[blockIdx.x] = incl;  // tile total
}

__global__ __launch_bounds__(512) void scan2_kernel(int* __restrict__ tsums, int nt) {
  __shared__ int buf[2][512];
  int tid = threadIdx.x;
  int v = (tid < nt) ? tsums[tid] : 0;
  int cur = 0;
  buf[0][tid] = v;
  __syncthreads();
#pragma unroll
  for (int off = 1; off < 512; off <<= 1) {
    int t = buf[cur][tid];
    if (tid >= off) t += buf[cur][tid - off];
    buf[cur ^ 1][tid] = t;
    cur ^= 1;
    __syncthreads();
  }
  if (tid < nt) tsums[tid] = buf[cur][tid] - v;  // exclusive tile offsets
}

__global__ __launch_bounds__(512) void scan3_kernel(int* __restrict__ cursor,
                                                    const int* __restrict__ tsums, int n) {
  int i = blockIdx.x * 512 + threadIdx.x;
  if (i < n) cursor[i] += tsums[blockIdx.x];
}

__global__ __launch_bounds__(256) void scatter_kernel(const int* __restrict__ idx, int nE,
                                                      int* __restrict__ cursor,
                                                      int* __restrict__ si, int* __restrict__ sj) {
  int e = blockIdx.x * 256 + threadIdx.x;
  int st = gridDim.x * 256;
  for (; e < nE; e += st) {
    int i = idx[e], j = idx[nE + e];
    int p = atomicAdd(&cursor[j], 1);
    si[p] = i;
    sj[p] = j;
  }
}

// --------------------------------------------------- weight transpose ----
struct WTDesc {
  const float* src[11];
  int K[11];
  int off[11];
};
__global__ __launch_bounds__(128) void wt_kernel(WTDesc d, short* __restrict__ dst) {
  int m = blockIdx.x >> 7;
  int n = blockIdx.x & 127;
  const float* s = d.src[m];
  int K = d.K[m];
  short* o = dst + d.off[m] + (size_t)n * K;
  for (int k = threadIdx.x; k < K; k += 128) o[k] = f2bf(s[(size_t)k * 128 + n]);
}

// ------------------------------------------------------- MFMA helpers ----
// 64-row tile in LDS (bf16, 16B-chunk XOR swizzle: chunk ^= row&7).
// A-frag: row = lane&15 (+rf*16), k = (lane>>4)*8 + j (+ks*32)
// B-frag: col = lane&15 (+cf*16), same k pattern, from WT[N][K].
// C/D  : col = lane&15, row = (lane>>4)*4 + reg  [HW-verified]
template <int K>
static __device__ __forceinline__ void mfma_gemm(const short* __restrict__ sA, int rs16,
                                                 const short* __restrict__ WT,
                                                 int c0, int lane,
                                                 const float* __restrict__ bias,
                                                 f4 (&acc)[4][2]) {
  const int colA = c0 + (lane & 15);
  const int colB = colA + 16;
  if (bias) {
    float ba = bias[colA], bb = bias[colB];
#pragma unroll
    for (int rf = 0; rf < 4; ++rf) {
      acc[rf][0] = (f4){ba, ba, ba, ba};
      acc[rf][1] = (f4){bb, bb, bb, bb};
    }
  } else {
#pragma unroll
    for (int rf = 0; rf < 4; ++rf) {
      acc[rf][0] = (f4){0.f, 0.f, 0.f, 0.f};
      acc[rf][1] = (f4){0.f, 0.f, 0.f, 0.f};
    }
  }
  const int g = lane >> 4;
  const int rowl = lane & 15;
#pragma unroll 4
  for (int ks = 0; ks < (K >> 5); ++ks) {
    bf8 b0 = *reinterpret_cast<const bf8*>(WT + (size_t)colA * K + ks * 32 + g * 8);
    bf8 b1 = *reinterpret_cast<const bf8*>(WT + (size_t)colB * K + ks * 32 + g * 8);
    int chunk = ks * 4 + g;
#pragma unroll
    for (int rf = 0; rf < 4; ++rf) {
      int row = rf * 16 + rowl;
      bf8 a = *reinterpret_cast<const bf8*>(sA + row * rs16 * 8 + ((chunk ^ (row & 7)) << 3));
      acc[rf][0] = __builtin_amdgcn_mfma_f32_16x16x32_bf16(a, b0, acc[rf][0], 0, 0, 0);
      acc[rf][1] = __builtin_amdgcn_mfma_f32_16x16x32_bf16(a, b1, acc[rf][1], 0, 0, 0);
    }
  }
}

template <bool RELU, bool SWZ>
static __device__ __forceinline__ void store_frags(short* __restrict__ dst, int rs16,
                                                   int c0, int lane, const f4 (&acc)[4][2]) {
#pragma unroll
  for (int rf = 0; rf < 4; ++rf)
#pragma unroll
    for (int q = 0; q < 4; ++q) {
      int row = rf * 16 + ((lane >> 4) << 2) + q;
#pragma unroll
      for (int cf = 0; cf < 2; ++cf) {
        int col = c0 + cf * 16 + (lane & 15);
        float v = acc[rf][cf][q];
        if (RELU) v = fmaxf(v, 0.f);
        int idx;
        if (SWZ) idx = row * rs16 * 8 + (((col >> 3) ^ (row & 7)) << 3) + (col & 7);
        else     idx = row * rs16 * 8 + col;
        dst[idx] = f2bf(v);
      }
    }
}

// per-row sum/sumsq over this wave's 32 cols -> sP[wave*64+row]
static __device__ __forceinline__ void ln_rows(const f4 (&acc)[4][2], int lane, int wave,
                                               float2* __restrict__ sP) {
#pragma unroll
  for (int rf = 0; rf < 4; ++rf)
#pragma unroll
    for (int q = 0; q < 4; ++q) {
      float v0 = acc[rf][0][q], v1 = acc[rf][1][q];
      float s = v0 + v1;
      float qq = v0 * v0 + v1 * v1;
      s += __shfl_xor(s, 1);  qq += __shfl_xor(qq, 1);
      s += __shfl_xor(s, 2);  qq += __shfl_xor(qq, 2);
      s += __shfl_xor(s, 4);  qq += __shfl_xor(qq, 4);
      s += __shfl_xor(s, 8);  qq += __shfl_xor(qq, 8);
      if ((lane & 15) == 0) {
        int row = rf * 16 + ((lane >> 4) << 2) + q;
        sP[wave * 64 + row] = make_float2(s, qq);
      }
    }
}

// ------------------------------------------------------------ precompute ----
__global__ __launch_bounds__(256) void precompute_kernel(
    const float* __restrict__ x, const short* __restrict__ WTp,
    short* __restrict__ xa_m, short* __restrict__ xb_m,
    short* __restrict__ xa_c, short* __restrict__ xb_c) {
  __shared__ __align__(16) short sA[64 * 128];
  __shared__ __align__(16) short sOut[64 * 128];
  const int tid = threadIdx.x;
  const int lane = tid & 63, wave = tid >> 6;
  const int c0 = wave * 32;
  const int n0 = blockIdx.x * 64;

#pragma unroll
  for (int it = 0; it < 4; ++it) {
    int s = it * 256 + tid;
    int e = s >> 4, c = s & 15;
    int n = n0 + e;
    f4 u0 = {0.f, 0.f, 0.f, 0.f}, u1 = {0.f, 0.f, 0.f, 0.f};
    if (n < NN) {
      u0 = *reinterpret_cast<const f4*>(x + (size_t)n * 128 + c * 8);
      u1 = *reinterpret_cast<const f4*>(x + (size_t)n * 128 + c * 8 + 4);
    }
    bf8 o;
#pragma unroll
    for (int j = 0; j < 4; ++j) { o[j] = f2bf(u0[j]); o[j + 4] = f2bf(u1[j]); }
    *reinterpret_cast<bf8*>(sA + e * 128 + ((c ^ (e & 7)) << 3)) = o;
  }
  __syncthreads();

  short* dsts[4] = {xa_m, xb_m, xa_c, xb_c};
#pragma unroll 1
  for (int o = 0; o < 4; ++o) {
    f4 acc[4][2];
    mfma_gemm<128>(sA, 16, WTp + o * 16384, c0, lane, nullptr, acc);
    store_frags<false, false>(sOut, 16, c0, lane, acc);
    __syncthreads();
    short* dst = dsts[o];
#pragma unroll
    for (int it = 0; it < 4; ++it) {
      int s = it * 256 + tid;
      int e = s >> 4, c = s & 15;
      int n = n0 + e;
      if (n < NN)
        *reinterpret_cast<bf8*>(dst + (size_t)n * 128 + c * 8) =
            *reinterpret_cast<const bf8*>(sOut + e * 128 + c * 8);
    }
    __syncthreads();
  }
}

// ------------------------------------------------------------ edge MLP ----
// Edges pre-sorted by j. Segmented reduction replaces per-edge scatter.
template <int NF>
__global__ __launch_bounds__(256) void edge_kernel(
    const int* __restrict__ si, const int* __restrict__ sjv, int nE,
    const float* __restrict__ pp,
    const short* __restrict__ xa, const short* __restrict__ xb,
    const float* __restrict__ W0f, const float* __restrict__ b0v,
    const short* __restrict__ WT1, const float* __restrict__ b1v,
    const short* __restrict__ WT2, const float* __restrict__ b2v,
    float* __restrict__ agg) {
  // sAB: [0,8192) h0 bf16 swizzled; [8192,16384) h1 bf16 swizzled;
  // then the whole 32KB is reused as f32 [64][128] normalized-h2 tile.
  __shared__ __align__(16) short sAB[2 * 64 * 128];
  __shared__ int sI[64], sJ[64];
  __shared__ float sF[64][NF];
  __shared__ float2 sP[4 * 64];
  __shared__ float2 sStats[64];
  const int tid = threadIdx.x;
  const int lane = tid & 63, wave = tid >> 6;
  const int c0 = wave * 32;
  const int base = xcd_swizzle(blockIdx.x, gridDim.x) * 64;
  short* sA = sAB;
  short* sB = sAB + 64 * 128;
  float* sT = reinterpret_cast<float*>(sAB);

  if (tid < 64) {
    int e = base + tid;
    int i = si[e];
    int j = sjv[e];
    sI[tid] = i; sJ[tid] = j;
    const float* pi = pp + (size_t)i * 6;
    const float* pj = pp + (size_t)j * 6;
    if (NF == 8) {
      float d0 = pi[0] - pj[0], d1 = pi[1] - pj[1], d2 = pi[2] - pj[2];
      sF[tid][0] = d0; sF[tid][1] = d1; sF[tid][2] = d2;
      sF[tid][3] = sqrtf(d0 * d0 + d1 * d1 + d2 * d2);
      float w0 = pi[3] - pj[3], w1 = pi[4] - pj[4], w2 = pi[5] - pj[5];
      sF[tid][4] = w0; sF[tid][5] = w1; sF[tid][6] = w2;
      sF[tid][7] = sqrtf(w0 * w0 + w1 * w1 + w2 * w2);
    } else {
      float w0 = pi[3] - pj[3], w1 = pi[4] - pj[4], w2 = pi[5] - pj[5];
      sF[tid][0] = w0; sF[tid][1] = w1; sF[tid][2] = w2;
      sF[tid][3] = sqrtf(w0 * w0 + w1 * w1 + w2 * w2);
    }
  }
  __syncthreads();

  // stage h0 = relu(xa[i] + xb[j] + b0 + feat@W0f) as bf16 (swizzled)
#pragma unroll
  for (int it = 0; it < 4; ++it) {
    int s = it * 256 + tid;
    int e = s >> 4, c = s & 15;
    int i = sI[e], j = sJ[e];
    bf8 va = *reinterpret_cast<const bf8*>(xa + (size_t)i * 128 + c * 8);
    bf8 vb = *reinterpret_cast<const bf8*>(xb + (size_t)j * 128 + c * 8);
    f4 b0a = *reinterpret_cast<const f4*>(b0v + c * 8);
    f4 b0b = *reinterpret_cast<const f4*>(b0v + c * 8 + 4);
    float h[8];
#pragma unroll
    for (int jj = 0; jj < 4; ++jj) {
      h[jj]     = bf2f(va[jj])     + bf2f(vb[jj])     + b0a[jj];
      h[jj + 4] = bf2f(va[jj + 4]) + bf2f(vb[jj + 4]) + b0b[jj];
    }
#pragma unroll
    for (int q = 0; q < NF; ++q) {
      float fq = sF[e][q];
      f4 w0 = *reinterpret_cast<const f4*>(W0f + q * 128 + c * 8);
      f4 w1 = *reinterpret_cast<const f4*>(W0f + q * 128 + c * 8 + 4);
#pragma unroll
      for (int jj = 0; jj < 4; ++jj) {
        h[jj]     = fmaf(fq, w0[jj], h[jj]);
        h[jj + 4] = fmaf(fq, w1[jj], h[jj + 4]);
      }
    }
    bf8 o;
#pragma unroll
    for (int jj = 0; jj < 8; ++jj) o[jj] = f2bf(fmaxf(h[jj], 0.f));
    *reinterpret_cast<bf8*>(sA + e * 128 + ((c ^ (e & 7)) << 3)) = o;
  }
  __syncthreads();

  f4 acc[4][2];
  mfma_gemm<128>(sA, 16, WT1, c0, lane, b1v, acc);   // h1 = relu(h0)@W1+b1
  store_frags<true, true>(sB, 16, c0, lane, acc);
  __syncthreads();
  mfma_gemm<128>(sB, 16, WT2, c0, lane, b2v, acc);   // h2 = relu(h1)@W2+b2

  ln_rows(acc, lane, wave, sP);
  __syncthreads();                                    // also: all GEMM2 reads done
  if (tid < 64) {
    float s = 0.f, qq = 0.f;
#pragma unroll
    for (int w = 0; w < 4; ++w) { s += sP[w * 64 + tid].x; qq += sP[w * 64 + tid].y; }
    float mean = s * (1.f / 128.f);
    float var = qq * (1.f / 128.f) - mean * mean;
    sStats[tid] = make_float2(mean, rsqrtf(var + 1e-5f));
  }
  __syncthreads();

  // normalized h2 -> f32 LDS tile (overwrites sA/sB, both dead)
#pragma unroll
  for (int rf = 0; rf < 4; ++rf)
#pragma unroll
    for (int q = 0; q < 4; ++q) {
      int row = rf * 16 + ((lane >> 4) << 2) + q;
      float mean = sStats[row].x, rn = sStats[row].y;
#pragma unroll
      for (int cf = 0; cf < 2; ++cf) {
        int col = c0 + cf * 16 + (lane & 15);
        sT[row * 128 + col] = (acc[rf][cf][q] - mean) * rn;
      }
    }
  __syncthreads();

  // segmented column sums: one atomic per (segment, col)
  {
    int grp = tid >> 7, c = tid & 127;
    int r0 = grp * 32;
    float accum = 0.f;
#pragma unroll 4
    for (int r = r0; r < r0 + 32; ++r) {
      accum += sT[r * 128 + c];
      bool flush = (r == r0 + 31) || (sJ[r + 1] != sJ[r]);
      if (flush) {
        unsafeAtomicAdd(agg + (size_t)sJ[r] * 128 + c, accum);
        accum = 0.f;
      }
    }
  }
}

// ------------------------------------------------------------ node MLP ----
__global__ __launch_bounds__(256) void node_kernel(
    const float* __restrict__ x,
    const float* __restrict__ agg_m, const float* __restrict__ agg_c,
    const short* __restrict__ WT0, const float* __restrict__ b0v,
    const short* __restrict__ WT1, const float* __restrict__ b1v,
    const short* __restrict__ WT2, const float* __restrict__ b2v,
    float* __restrict__ out) {
  __shared__ __align__(16) short sA[64 * 384];
  __shared__ float2 sP[4 * 64];
  __shared__ float2 sStats[64];
  const int tid = threadIdx.x;
  const int lane = tid & 63, wave = tid >> 6;
  const int c0 = wave * 32;
  const int n0 = blockIdx.x * 64;

#pragma unroll
  for (int p = 0; p < 3; ++p) {
    const float* src = (p == 0) ? x : (p == 1) ? agg_m : agg_c;
#pragma unroll
    for (int it = 0; it < 4; ++it) {
      int s = it * 256 + tid;
      int e = s >> 4, cl = s & 15;
      int n = n0 + e;
      f4 u0 = {0.f, 0.f, 0.f, 0.f}, u1 = {0.f, 0.f, 0.f, 0.f};
      if (n < NN) {
        u0 = *reinterpret_cast<const f4*>(src + (size_t)n * 128 + cl * 8);
        u1 = *reinterpret_cast<const f4*>(src + (size_t)n * 128 + cl * 8 + 4);
      }
      bf8 o;
#pragma unroll
      for (int j = 0; j < 4; ++j) { o[j] = f2bf(u0[j]); o[j + 4] = f2bf(u1[j]); }
      int c = p * 16 + cl;
      *reinterpret_cast<bf8*>(sA + e * 384 + ((c ^ (e & 7)) << 3)) = o;
    }
  }
  __syncthreads();

  f4 acc[4][2];
  mfma_gemm<384>(sA, 48, WT0, c0, lane, b0v, acc);
  __syncthreads();
  store_frags<true, true>(sA, 16, c0, lane, acc);
  __syncthreads();
  mfma_gemm<128>(sA, 16, WT1, c0, lane, b1v, acc);
  __syncthreads();
  store_frags<true, true>(sA + 8192, 16, c0, lane, acc);
  __syncthreads();
  mfma_gemm<128>(sA + 8192, 16, WT2, c0, lane, b2v, acc);

  ln_rows(acc, lane, wave, sP);
  __syncthreads();
  if (tid < 64) {
    float s = 0.f, qq = 0.f;
#pragma unroll
    for (int w = 0; w < 4; ++w) { s += sP[w * 64 + tid].x; qq += sP[w * 64 + tid].y; }
    float mean = s * (1.f / 128.f);
    float var = qq * (1.f / 128.f) - mean * mean;
    sStats[tid] = make_float2(mean, rsqrtf(var + 1e-5f));
  }
  __syncthreads();

#pragma unroll
  for (int rf = 0; rf < 4; ++rf)
#pragma unroll
    for (int q = 0; q < 4; ++q) {
      int row = rf * 16 + ((lane >> 4) << 2) + q;
      int n = n0 + row;
      if (n < NN) {
        float mean = sStats[row].x, rn = sStats[row].y;
#pragma unroll
        for (int cf = 0; cf < 2; ++cf) {
          int col = c0 + cf * 16 + (lane & 15);
          float xv = x[(size_t)n * 128 + col];
          out[(size_t)n * 128 + col] = (acc[rf][cf][q] - mean) * rn + xv;
        }
      }
    }
}

// -------------------------------------------------------------- launch ----
extern "C" void kernel_launch(void* const* d_in, const int* in_sizes, int n_in,
                              void* d_out, int out_size, void* d_ws, size_t ws_size,
                              hipStream_t stream) {
  const float* x   = (const float*)d_in[0];
  const int*   g   = (const int*)d_in[1];
  const int*   cgr = (const int*)d_in[2];
  const float* pp  = (const float*)d_in[3];
  const float* mW0 = (const float*)d_in[4];
  const float* mb0 = (const float*)d_in[5];
  const float* mW1 = (const float*)d_in[6];
  const float* mb1 = (const float*)d_in[7];
  const float* mW2 = (const float*)d_in[8];
  const float* mb2 = (const float*)d_in[9];
  const float* cW0 = (const float*)d_in[10];
  const float* cb0 = (const float*)d_in[11];
  const float* cW1 = (const float*)d_in[12];
  const float* cb1 = (const float*)d_in[13];
  const float* cW2 = (const float*)d_in[14];
  const float* cb2 = (const float*)d_in[15];
  const float* nW0 = (const float*)d_in[16];
  const float* nb0 = (const float*)d_in[17];
  const float* nW1 = (const float*)d_in[18];
  const float* nb1 = (const float*)d_in[19];
  const float* nW2 = (const float*)d_in[20];
  const float* nb2 = (const float*)d_in[21];
  float* out = (float*)d_out;

  // ---- weight transpose packing (compute total size FIRST) ----
  WTDesc d;
  const float* srcs[11] = {mW1, mW2, cW1, cW2, nW0, nW1, nW2,
                           mW0 + 8 * 128, mW0 + 136 * 128, cW0 + 4 * 128, cW0 + 132 * 128};
  int Ks[11] = {128, 128, 128, 128, 384, 128, 128, 128, 128, 128, 128};
  int off = 0;
  for (int m = 0; m < 11; ++m) { d.src[m] = srcs[m]; d.K[m] = Ks[m]; d.off[m] = off; off += Ks[m] * 128; }
  // off = 212992 elems = 425984 bytes (was wrongly hard-coded 1536*128*2 in R3 -> overlap!)

  // ---- workspace layout ----
  char* ws = (char*)d_ws;
  const size_t TBL = (size_t)NN * 128 * 2;        // 12.8 MB (bf16 table)
  const size_t AGG = (size_t)NN * 128 * 4;        // 25.6 MB (f32 agg)
  short* xa_m = (short*)(ws);
  short* xb_m = (short*)(ws + TBL);
  short* xa_c = (short*)(ws + 2 * TBL);
  short* xb_c = (short*)(ws + 3 * TBL);
  float* agg_m = (float*)(ws + 4 * TBL);
  float* agg_c = (float*)(ws + 4 * TBL + AGG);
  short* wt = (short*)(ws + 4 * TBL + 2 * AGG);
  char* ib = ws + 4 * TBL + 2 * AGG + (size_t)off * 2;   // after FULL wt buffer (16B aligned)
  int* hist_m   = (int*)(ib);
  int* hist_c   = hist_m + NP;
  int* cursor_m = hist_c + NP;
  int* cursor_c = cursor_m + NP;
  int* tsum_m   = cursor_c + NP;
  int* tsum_c   = tsum_m + 128;
  int* si_m     = tsum_c + 128;
  int* sj_m     = si_m + NE_MAIN;
  int* si_c     = sj_m + NE_MAIN;
  int* sj_c     = si_c + NE_CONT;

  short* wt1_m = wt + d.off[0];
  short* wt2_m = wt + d.off[1];
  short* wt1_c = wt + d.off[2];
  short* wt2_c = wt + d.off[3];
  short* wtn0  = wt + d.off[4];
  short* wtn1  = wt + d.off[5];
  short* wtn2  = wt + d.off[6];
  short* wtp   = wt + d.off[7];

  const int NT = (NN + 511) / 512;   // 98 scan tiles

  wt_kernel<<<11 * 128, 128, 0, stream>>>(d, wt);
  zero_kernel<<<2048, 256, 0, stream>>>((f4*)agg_m, (int)(2 * (size_t)NN * 128 / 4));
  zero_kernel<<<128, 256, 0, stream>>>((f4*)hist_m, 2 * NP / 4);

  // counting sort by j (both edge sets)
  hist_kernel<<<1024, 256, 0, stream>>>(g, NE_MAIN, hist_m);
  hist_kernel<<<512, 256, 0, stream>>>(cgr, NE_CONT, hist_c);
  scan1_kernel<<<NT, 512, 0, stream>>>(hist_m, cursor_m, tsum_m, NN);
  scan1_kernel<<<NT, 512, 0, stream>>>(hist_c, cursor_c, tsum_c, NN);
  scan2_kernel<<<1, 512, 0, stream>>>(tsum_m, NT);
  scan2_kernel<<<1, 512, 0, stream>>>(tsum_c, NT);
  scan3_kernel<<<NT, 512, 0, stream>>>(cursor_m, tsum_m, NN);
  scan3_kernel<<<NT, 512, 0, stream>>>(cursor_c, tsum_c, NN);
  scatter_kernel<<<1024, 256, 0, stream>>>(g, NE_MAIN, cursor_m, si_m, sj_m);
  scatter_kernel<<<512, 256, 0, stream>>>(cgr, NE_CONT, cursor_c, si_c, sj_c);

  precompute_kernel<<<(NN + 63) / 64, 256, 0, stream>>>(x, wtp, xa_m, xb_m, xa_c, xb_c);
  edge_kernel<8><<<NE_MAIN / 64, 256, 0, stream>>>(si_m, sj_m, NE_MAIN, pp, xa_m, xb_m,
                                                   mW0, mb0, wt1_m, mb1, wt2_m, mb2, agg_m);
  edge_kernel<4><<<NE_CONT / 64, 256, 0, stream>>>(si_c, sj_c, NE_CONT, pp, xa_c, xb_c,
                                                   cW0, cb0, wt1_c, cb1, wt2_c, cb2, agg_c);
  node_kernel<<<(NN + 63) / 64, 256, 0, stream>>>(x, agg_m, agg_c,
                                                  wtn0, nb0, wtn1, nb1, wtn2, nb2, out);
}